// Round 3
// baseline (244.556 us; speedup 1.0000x reference)
//
#include <hip/hip_runtime.h>
#include <hip/hip_bf16.h>
#include <cmath>

#define NB 16384   // batch rows
#define NK 512     // in features
#define NO 1024    // out features (centres)
#define NC 5       // classes

typedef float f32x4 __attribute__((ext_vector_type(4)));
typedef short s16x8 __attribute__((ext_vector_type(8)));

__device__ inline short f2bf(float f) {
    union { __hip_bfloat16 h; short s; } u;
    u.h = __float2bfloat16(f);
    return u.s;
}

// ---------------------------------------------------------------------------
// Kernel 1: fused row sum-of-squares (f32) + bf16 conversion of X and C.
// One wave per row: 512 f32 = 8 per lane. Reads 35 MB, writes 18 MB.
// ---------------------------------------------------------------------------
__global__ void prep_bf16(const float* __restrict__ x, const float* __restrict__ c,
                          short* __restrict__ xbf, short* __restrict__ cbf,
                          float* __restrict__ x2, float* __restrict__ c2) {
    int gw   = (blockIdx.x * blockDim.x + threadIdx.x) >> 6;
    int lane = threadIdx.x & 63;
    if (gw >= NB + NO) return;
    bool isX = gw < NB;
    const float* src = isX ? (x + (size_t)gw * NK) : (c + (size_t)(gw - NB) * NK);
    short*       dst = isX ? (xbf + (size_t)gw * NK) : (cbf + (size_t)(gw - NB) * NK);
    f32x4 v0 = *(const f32x4*)(src + lane * 8);
    f32x4 v1 = *(const f32x4*)(src + lane * 8 + 4);
    s16x8 o;
    float s = 0.f;
#pragma unroll
    for (int j = 0; j < 4; ++j) {
        s += v0[j] * v0[j] + v1[j] * v1[j];
        o[j]     = f2bf(v0[j]);
        o[4 + j] = f2bf(v1[j]);
    }
    *(s16x8*)(dst + lane * 8) = o;
#pragma unroll
    for (int off = 1; off < 64; off <<= 1) s += __shfl_xor(s, off);
    if (lane == 0) {
        if (isX) x2[gw] = s;
        else     c2[gw - NB] = s;
    }
}

// Standalone prep for the fallback path (no bf16 staging space in ws).
__global__ void prep_f32(const float* __restrict__ x, const float* __restrict__ c,
                         float* __restrict__ x2, float* __restrict__ c2) {
    int gw   = (blockIdx.x * blockDim.x + threadIdx.x) >> 6;
    int lane = threadIdx.x & 63;
    if (gw >= NB + NO) return;
    const float* src = (gw < NB) ? (x + (size_t)gw * NK)
                                 : (c + (size_t)(gw - NB) * NK);
    f32x4 v0 = *(const f32x4*)(src + lane * 8);
    f32x4 v1 = *(const f32x4*)(src + lane * 8 + 4);
    float s = 0.f;
#pragma unroll
    for (int j = 0; j < 4; ++j) s += v0[j] * v0[j] + v1[j] * v1[j];
#pragma unroll
    for (int off = 1; off < 64; off <<= 1) s += __shfl_xor(s, off);
    if (lane == 0) {
        if (gw < NB) x2[gw] = s;
        else         c2[gw - NB] = s;
    }
}

// ---------------------------------------------------------------------------
// Kernel 2: out[b][n] = fc_b[n]  (d_out is 0xAA-poisoned before every call).
// ---------------------------------------------------------------------------
__global__ void init_out(float* __restrict__ out, const float* __restrict__ fcb) {
    int i = blockIdx.x * blockDim.x + threadIdx.x;
    if (i < NB * NC) out[i] = fcb[i % NC];
}

// ---------------------------------------------------------------------------
// Shared epilogue: acc (X.C^T frags) -> sq -> basis -> 5-class reduce+atomic.
// C layout (16x16x32): col = lane&15, row = (lane>>4)*4 + reg   [m89/m91]
// ---------------------------------------------------------------------------
__device__ inline void rbf_epilogue(f32x4 acc[4][4],
                                    const float* __restrict__ x2,
                                    const float* __restrict__ c2,
                                    const float* __restrict__ ls,
                                    const float* __restrict__ fcw,
                                    float* __restrict__ out,
                                    int bm, int bn, int wr, int wc,
                                    int lc, int kg) {
    const int growb0 = bm * 128 + wr * 64 + kg * 4;  // + mi*16 + r
    const int gcol0  = bn * 128 + wc * 64 + lc;      // + ni*16

    float c2v[4], invs2[4], w[4][5];
#pragma unroll
    for (int ni = 0; ni < 4; ++ni) {
        int gc = gcol0 + ni * 16;
        c2v[ni]   = c2[gc];
        invs2[ni] = expf(-2.f * ls[gc]);   // 1/sigma^2; basis = exp(-sq/sigma^2)
#pragma unroll
        for (int n = 0; n < 5; ++n) w[ni][n] = fcw[n * NO + gc];
    }

#pragma unroll
    for (int mi = 0; mi < 4; ++mi) {
        float rs[4][5];
#pragma unroll
        for (int r = 0; r < 4; ++r)
#pragma unroll
            for (int n = 0; n < 5; ++n) rs[r][n] = 0.f;

#pragma unroll
        for (int r = 0; r < 4; ++r) {
            float x2v = x2[growb0 + mi * 16 + r];
#pragma unroll
            for (int ni = 0; ni < 4; ++ni) {
                float sq    = fmaxf(x2v + c2v[ni] - 2.f * acc[mi][ni][r], 0.f);
                float basis = expf(-sq * invs2[ni]);
#pragma unroll
                for (int n = 0; n < 5; ++n) rs[r][n] += basis * w[ni][n];
            }
        }
#pragma unroll
        for (int off = 1; off < 16; off <<= 1)
#pragma unroll
            for (int r = 0; r < 4; ++r)
#pragma unroll
                for (int n = 0; n < 5; ++n) rs[r][n] += __shfl_xor(rs[r][n], off);

        if (lc == 0) {
#pragma unroll
            for (int r = 0; r < 4; ++r) {
                int grow = growb0 + mi * 16 + r;
#pragma unroll
                for (int n = 0; n < 5; ++n)
                    atomicAdd(&out[(size_t)grow * NC + n], rs[r][n]);
            }
        }
    }
}

// ---------------------------------------------------------------------------
// Kernel 3 (main path): double-buffered 2-phase GEMM on pre-converted bf16.
// 128x128 tile, BK=32, 4 waves (2x2). Per K-step: issue STAGE(t+1) into the
// other LDS buffer FIRST, then ds_read+MFMA tile t, then ONE __syncthreads
// (its vmcnt(0) drain lands after the compute phase hid most of the latency).
// XCD-chunked block remap: each XCD owns 16 bm x 8 bn -> A-chunk 2MB + B 1MB
// resident in its 4MB L2.
// ---------------------------------------------------------------------------
__global__ __launch_bounds__(256)
void rbf_gemm_bf16(const short* __restrict__ Abf, const short* __restrict__ Bbf,
                   const float* __restrict__ x2, const float* __restrict__ c2,
                   const float* __restrict__ ls, const float* __restrict__ fcw,
                   float* __restrict__ out) {
    __shared__ short As[2][128 * 32];
    __shared__ short Bs[2][128 * 32];

    const int t    = threadIdx.x;
    const int lane = t & 63, wave = t >> 6;
    const int wr = wave >> 1, wc = wave & 1;
    const int lc = lane & 15, kg = lane >> 4;

    // bijective XCD-chunk remap (nwg=1024, 1024%8==0): orig%8 = XCD id.
    const int orig = blockIdx.x;
    const int wg   = (orig >> 3) + (orig & 7) * (1024 / 8);
    const int bm = wg >> 3, bn = wg & 7;

    // staging: thread t covers short index (j*256+t)*8 of row-major [128][32]
    // -> row = j*64 + wave*16 + (lane>>2), col = (lane&3)*8.
    const int srow = wave * 16 + (lane >> 2);
    const int scol = (lane & 3) * 8;
    const short* gA = Abf + (size_t)(bm * 128 + srow) * NK + scol;
    const short* gB = Bbf + (size_t)(bn * 128 + srow) * NK + scol;

#define STAGE(buf, kt)                                                          \
    _Pragma("unroll")                                                           \
    for (int j = 0; j < 2; ++j) {                                               \
        __builtin_amdgcn_global_load_lds(                                       \
            (const __attribute__((address_space(1))) unsigned int*)(gA + (size_t)j * 64 * NK + (kt) * 32), \
            (__attribute__((address_space(3))) unsigned int*)(&As[buf][wave * 512 + j * 2048]), \
            16, 0, 0);                                                          \
        __builtin_amdgcn_global_load_lds(                                       \
            (const __attribute__((address_space(1))) unsigned int*)(gB + (size_t)j * 64 * NK + (kt) * 32), \
            (__attribute__((address_space(3))) unsigned int*)(&Bs[buf][wave * 512 + j * 2048]), \
            16, 0, 0);                                                          \
    }

    f32x4 acc[4][4];
#pragma unroll
    for (int i = 0; i < 4; ++i)
#pragma unroll
        for (int j = 0; j < 4; ++j)
#pragma unroll
            for (int k = 0; k < 4; ++k) acc[i][j][k] = 0.f;

    const int aoff = (wr * 64 + lc) * 32 + kg * 8;
    const int boff = (wc * 64 + lc) * 32 + kg * 8;

#define COMPUTE(buf)                                                            \
    {                                                                           \
        s16x8 af[4], bfv[4];                                                    \
        _Pragma("unroll")                                                       \
        for (int mi = 0; mi < 4; ++mi) af[mi]  = *(const s16x8*)(&As[buf][aoff + mi * 512]); \
        _Pragma("unroll")                                                       \
        for (int ni = 0; ni < 4; ++ni) bfv[ni] = *(const s16x8*)(&Bs[buf][boff + ni * 512]); \
        __builtin_amdgcn_s_setprio(1);                                          \
        _Pragma("unroll")                                                       \
        for (int mi = 0; mi < 4; ++mi)                                          \
            _Pragma("unroll")                                                   \
            for (int ni = 0; ni < 4; ++ni)                                      \
                acc[mi][ni] = __builtin_amdgcn_mfma_f32_16x16x32_bf16(          \
                    af[mi], bfv[ni], acc[mi][ni], 0, 0, 0);                     \
        __builtin_amdgcn_s_setprio(0);                                          \
    }

    STAGE(0, 0);
    __syncthreads();                 // drain: tile 0 in LDS
#pragma unroll
    for (int kt = 0; kt < NK / 32; kt += 2) {
        STAGE(1, kt + 1);            // always valid: kt+1 <= 15
        COMPUTE(0);
        __syncthreads();             // tile kt+1 landed; buf0 free
        if (kt + 2 < NK / 32) STAGE(0, kt + 2);
        COMPUTE(1);
        __syncthreads();             // tile kt+2 landed; buf1 free
    }
#undef STAGE
#undef COMPUTE

    rbf_epilogue(acc, x2, c2, ls, fcw, out, bm, bn, wr, wc, lc, kg);
}

// ---------------------------------------------------------------------------
// Fallback (ws too small): f32 reg-staged. Known-correct from round 1.
// ---------------------------------------------------------------------------
__global__ __launch_bounds__(256)
void rbf_gemm_f32(const float* __restrict__ X, const float* __restrict__ Cn,
                  const float* __restrict__ x2, const float* __restrict__ c2,
                  const float* __restrict__ ls, const float* __restrict__ fcw,
                  float* __restrict__ out) {
    __shared__ short As[128 * 40];
    __shared__ short Bs[128 * 40];

    const int t    = threadIdx.x;
    const int lane = t & 63, wave = t >> 6;
    const int wr = wave >> 1, wc = wave & 1;
    const int lc = lane & 15, kg = lane >> 4;
    const int bn = blockIdx.x & 7, bm = blockIdx.x >> 3;

    const int srow = t >> 1, shalf = t & 1;
    const float* pA = X  + (size_t)(bm * 128 + srow) * NK + shalf * 16;
    const float* pB = Cn + (size_t)(bn * 128 + srow) * NK + shalf * 16;
    const int sbase = srow * 40 + shalf * 16;

    f32x4 ra[4], rb[4];
#pragma unroll
    for (int i = 0; i < 4; ++i) {
        ra[i] = *(const f32x4*)(pA + i * 4);
        rb[i] = *(const f32x4*)(pB + i * 4);
    }

    f32x4 acc[4][4];
#pragma unroll
    for (int i = 0; i < 4; ++i)
#pragma unroll
        for (int j = 0; j < 4; ++j)
#pragma unroll
            for (int k = 0; k < 4; ++k) acc[i][j][k] = 0.f;

    const short* Ab = As + (wr * 64 + lc) * 40 + kg * 8;
    const short* Bb = Bs + (wc * 64 + lc) * 40 + kg * 8;

    for (int kt = 0; kt < NK / 32; ++kt) {
        __syncthreads();
        s16x8 va0, va1, vb0, vb1;
#pragma unroll
        for (int i = 0; i < 8; ++i) {
            va0[i] = f2bf(ra[i >> 2][i & 3]);
            va1[i] = f2bf(ra[2 + (i >> 2)][i & 3]);
            vb0[i] = f2bf(rb[i >> 2][i & 3]);
            vb1[i] = f2bf(rb[2 + (i >> 2)][i & 3]);
        }
        *(s16x8*)&As[sbase]     = va0;
        *(s16x8*)&As[sbase + 8] = va1;
        *(s16x8*)&Bs[sbase]     = vb0;
        *(s16x8*)&Bs[sbase + 8] = vb1;
        __syncthreads();

        if (kt + 1 < NK / 32) {
            const float* qA = pA + (kt + 1) * 32;
            const float* qB = pB + (kt + 1) * 32;
#pragma unroll
            for (int i = 0; i < 4; ++i) {
                ra[i] = *(const f32x4*)(qA + i * 4);
                rb[i] = *(const f32x4*)(qB + i * 4);
            }
        }

        s16x8 af[4], bfv[4];
#pragma unroll
        for (int mi = 0; mi < 4; ++mi) af[mi]  = *(const s16x8*)(Ab + mi * 16 * 40);
#pragma unroll
        for (int ni = 0; ni < 4; ++ni) bfv[ni] = *(const s16x8*)(Bb + ni * 16 * 40);
#pragma unroll
        for (int mi = 0; mi < 4; ++mi)
#pragma unroll
            for (int ni = 0; ni < 4; ++ni)
                acc[mi][ni] = __builtin_amdgcn_mfma_f32_16x16x32_bf16(
                    af[mi], bfv[ni], acc[mi][ni], 0, 0, 0);
    }

    rbf_epilogue(acc, x2, c2, ls, fcw, out, bm, bn, wr, wc, lc, kg);
}

// ---------------------------------------------------------------------------
extern "C" void kernel_launch(void* const* d_in, const int* in_sizes, int n_in,
                              void* d_out, int out_size, void* d_ws, size_t ws_size,
                              hipStream_t stream) {
    const float* X   = (const float*)d_in[0];   // [16384, 512]
    const float* Cn  = (const float*)d_in[1];   // [1024, 512]
    const float* ls  = (const float*)d_in[2];   // [1024]
    const float* fcw = (const float*)d_in[3];   // [5, 1024]
    const float* fcb = (const float*)d_in[4];   // [5]
    float* out = (float*)d_out;                 // [16384, 5]

    const size_t xbf_b = (size_t)NB * NK * 2;   // 16.78 MB
    const size_t cbf_b = (size_t)NO * NK * 2;   //  1.05 MB
    const size_t need  = xbf_b + cbf_b + (NB + NO) * sizeof(float);

    init_out<<<(NB * NC + 255) / 256, 256, 0, stream>>>(out, fcb);

    if (ws_size >= need) {
        short* xbf = (short*)d_ws;
        short* cbf = xbf + (size_t)NB * NK;
        float* x2  = (float*)(cbf + (size_t)NO * NK);
        float* c2  = x2 + NB;
        prep_bf16<<<(NB + NO + 3) / 4, 256, 0, stream>>>(X, Cn, xbf, cbf, x2, c2);
        rbf_gemm_bf16<<<(NO / 128) * (NB / 128), 256, 0, stream>>>(xbf, cbf, x2, c2, ls, fcw, out);
    } else {
        float* x2 = (float*)d_ws;
        float* c2 = x2 + NB;
        prep_f32<<<(NB + NO + 3) / 4, 256, 0, stream>>>(X, Cn, x2, c2);
        rbf_gemm_f32<<<(NO / 128) * (NB / 128), 256, 0, stream>>>(X, Cn, x2, c2, ls, fcw, out);
    }
}

// Round 4
// 129.979 us; speedup vs baseline: 1.8815x; 1.8815x over previous
//
#include <hip/hip_runtime.h>
#include <hip/hip_bf16.h>
#include <cmath>

#define NB 16384   // batch rows
#define NK 512     // in features
#define NO 1024    // out features (centres)
#define NC 5       // classes
#define NSL 16     // partial slices = 8 bn-blocks x 2 wc-waves

typedef float f32x4 __attribute__((ext_vector_type(4)));
typedef short s16x8 __attribute__((ext_vector_type(8)));

__device__ inline short f2bf(float f) {
    union { __hip_bfloat16 h; short s; } u;
    u.h = __float2bfloat16(f);
    return u.s;
}

// ---------------------------------------------------------------------------
// Kernel 1: fused row sum-of-squares (f32) + bf16 conversion of X and C.
// ---------------------------------------------------------------------------
__global__ void prep_bf16(const float* __restrict__ x, const float* __restrict__ c,
                          short* __restrict__ xbf, short* __restrict__ cbf,
                          float* __restrict__ x2, float* __restrict__ c2) {
    int gw   = (blockIdx.x * blockDim.x + threadIdx.x) >> 6;
    int lane = threadIdx.x & 63;
    if (gw >= NB + NO) return;
    bool isX = gw < NB;
    const float* src = isX ? (x + (size_t)gw * NK) : (c + (size_t)(gw - NB) * NK);
    short*       dst = isX ? (xbf + (size_t)gw * NK) : (cbf + (size_t)(gw - NB) * NK);
    f32x4 v0 = *(const f32x4*)(src + lane * 8);
    f32x4 v1 = *(const f32x4*)(src + lane * 8 + 4);
    s16x8 o;
    float s = 0.f;
#pragma unroll
    for (int j = 0; j < 4; ++j) {
        s += v0[j] * v0[j] + v1[j] * v1[j];
        o[j]     = f2bf(v0[j]);
        o[4 + j] = f2bf(v1[j]);
    }
    *(s16x8*)(dst + lane * 8) = o;
#pragma unroll
    for (int off = 1; off < 64; off <<= 1) s += __shfl_xor(s, off);
    if (lane == 0) {
        if (isX) x2[gw] = s;
        else     c2[gw - NB] = s;
    }
}

// Standalone prep for the fallback path.
__global__ void prep_f32(const float* __restrict__ x, const float* __restrict__ c,
                         float* __restrict__ x2, float* __restrict__ c2) {
    int gw   = (blockIdx.x * blockDim.x + threadIdx.x) >> 6;
    int lane = threadIdx.x & 63;
    if (gw >= NB + NO) return;
    const float* src = (gw < NB) ? (x + (size_t)gw * NK)
                                 : (c + (size_t)(gw - NB) * NK);
    f32x4 v0 = *(const f32x4*)(src + lane * 8);
    f32x4 v1 = *(const f32x4*)(src + lane * 8 + 4);
    float s = 0.f;
#pragma unroll
    for (int j = 0; j < 4; ++j) s += v0[j] * v0[j] + v1[j] * v1[j];
#pragma unroll
    for (int off = 1; off < 64; off <<= 1) s += __shfl_xor(s, off);
    if (lane == 0) {
        if (gw < NB) x2[gw] = s;
        else         c2[gw - NB] = s;
    }
}

// ---------------------------------------------------------------------------
// Kernel 2 (fallback only): out[b][n] = fc_b[n].
// ---------------------------------------------------------------------------
__global__ void init_out(float* __restrict__ out, const float* __restrict__ fcb) {
    int i = blockIdx.x * blockDim.x + threadIdx.x;
    if (i < NB * NC) out[i] = fcb[i % NC];
}

// ---------------------------------------------------------------------------
// Kernel 4: sum 16 partial slices + bias -> out.  part[NSL][NB*NC].
// ---------------------------------------------------------------------------
__global__ void reduce_out(const float* __restrict__ part,
                           const float* __restrict__ fcb,
                           float* __restrict__ out) {
    int i = blockIdx.x * blockDim.x + threadIdx.x;   // group of 4 f32
    if (i >= NB * NC / 4) return;
    f32x4 s = {0.f, 0.f, 0.f, 0.f};
#pragma unroll
    for (int sl = 0; sl < NSL; ++sl)
        s += *(const f32x4*)(part + (size_t)sl * NB * NC + i * 4);
    f32x4 o;
#pragma unroll
    for (int j = 0; j < 4; ++j) o[j] = s[j] + fcb[(i * 4 + j) % NC];
    *(f32x4*)(out + i * 4) = o;
}

// ---------------------------------------------------------------------------
// Epilogue (partial-store version): acc -> sq -> basis -> per-wave 64-col
// partial, stored to part[bn*2+wc] with plain coalesced 80B stores.
// C layout (16x16x32): col = lane&15, row = (lane>>4)*4 + reg   [m89/m91]
// ---------------------------------------------------------------------------
__device__ inline void rbf_epilogue_part(f32x4 acc[4][4],
                                         const float* __restrict__ x2,
                                         const float* __restrict__ c2,
                                         const float* __restrict__ ls,
                                         const float* __restrict__ fcw,
                                         float* __restrict__ part,
                                         int bm, int bn, int wr, int wc,
                                         int lc, int kg) {
    const int growb0 = bm * 128 + wr * 64 + kg * 4;  // + mi*16 + r
    const int gcol0  = bn * 128 + wc * 64 + lc;      // + ni*16
    float* slice = part + (size_t)(bn * 2 + wc) * NB * NC;

    float c2v[4], invs2[4], w[4][5];
#pragma unroll
    for (int ni = 0; ni < 4; ++ni) {
        int gc = gcol0 + ni * 16;
        c2v[ni]   = c2[gc];
        invs2[ni] = expf(-2.f * ls[gc]);   // 1/sigma^2; basis = exp(-sq/sigma^2)
#pragma unroll
        for (int n = 0; n < 5; ++n) w[ni][n] = fcw[n * NO + gc];
    }

#pragma unroll
    for (int mi = 0; mi < 4; ++mi) {
        float rs[4][5];
#pragma unroll
        for (int r = 0; r < 4; ++r)
#pragma unroll
            for (int n = 0; n < 5; ++n) rs[r][n] = 0.f;

#pragma unroll
        for (int r = 0; r < 4; ++r) {
            float x2v = x2[growb0 + mi * 16 + r];
#pragma unroll
            for (int ni = 0; ni < 4; ++ni) {
                float sq    = fmaxf(x2v + c2v[ni] - 2.f * acc[mi][ni][r], 0.f);
                float basis = expf(-sq * invs2[ni]);
#pragma unroll
                for (int n = 0; n < 5; ++n) rs[r][n] += basis * w[ni][n];
            }
        }
#pragma unroll
        for (int off = 1; off < 16; off <<= 1)
#pragma unroll
            for (int r = 0; r < 4; ++r)
#pragma unroll
                for (int n = 0; n < 5; ++n) rs[r][n] += __shfl_xor(rs[r][n], off);

        if (lc == 0) {
            // rows growb0+mi*16 .. +3 -> 20 contiguous f32, 80B-aligned
            float* dst = slice + (size_t)(growb0 + mi * 16) * NC;
            f32x4 v0 = {rs[0][0], rs[0][1], rs[0][2], rs[0][3]};
            f32x4 v1 = {rs[0][4], rs[1][0], rs[1][1], rs[1][2]};
            f32x4 v2 = {rs[1][3], rs[1][4], rs[2][0], rs[2][1]};
            f32x4 v3 = {rs[2][2], rs[2][3], rs[2][4], rs[3][0]};
            f32x4 v4 = {rs[3][1], rs[3][2], rs[3][3], rs[3][4]};
            *(f32x4*)(dst)      = v0;
            *(f32x4*)(dst + 4)  = v1;
            *(f32x4*)(dst + 8)  = v2;
            *(f32x4*)(dst + 12) = v3;
            *(f32x4*)(dst + 16) = v4;
        }
    }
}

// Atomic epilogue (fallback path only).
__device__ inline void rbf_epilogue_atomic(f32x4 acc[4][4],
                                           const float* __restrict__ x2,
                                           const float* __restrict__ c2,
                                           const float* __restrict__ ls,
                                           const float* __restrict__ fcw,
                                           float* __restrict__ out,
                                           int bm, int bn, int wr, int wc,
                                           int lc, int kg) {
    const int growb0 = bm * 128 + wr * 64 + kg * 4;
    const int gcol0  = bn * 128 + wc * 64 + lc;
    float c2v[4], invs2[4], w[4][5];
#pragma unroll
    for (int ni = 0; ni < 4; ++ni) {
        int gc = gcol0 + ni * 16;
        c2v[ni]   = c2[gc];
        invs2[ni] = expf(-2.f * ls[gc]);
#pragma unroll
        for (int n = 0; n < 5; ++n) w[ni][n] = fcw[n * NO + gc];
    }
#pragma unroll
    for (int mi = 0; mi < 4; ++mi) {
        float rs[4][5];
#pragma unroll
        for (int r = 0; r < 4; ++r)
#pragma unroll
            for (int n = 0; n < 5; ++n) rs[r][n] = 0.f;
#pragma unroll
        for (int r = 0; r < 4; ++r) {
            float x2v = x2[growb0 + mi * 16 + r];
#pragma unroll
            for (int ni = 0; ni < 4; ++ni) {
                float sq    = fmaxf(x2v + c2v[ni] - 2.f * acc[mi][ni][r], 0.f);
                float basis = expf(-sq * invs2[ni]);
#pragma unroll
                for (int n = 0; n < 5; ++n) rs[r][n] += basis * w[ni][n];
            }
        }
#pragma unroll
        for (int off = 1; off < 16; off <<= 1)
#pragma unroll
            for (int r = 0; r < 4; ++r)
#pragma unroll
                for (int n = 0; n < 5; ++n) rs[r][n] += __shfl_xor(rs[r][n], off);
        if (lc == 0) {
#pragma unroll
            for (int r = 0; r < 4; ++r) {
                int grow = growb0 + mi * 16 + r;
#pragma unroll
                for (int n = 0; n < 5; ++n)
                    atomicAdd(&out[(size_t)grow * NC + n], rs[r][n]);
            }
        }
    }
}

// ---------------------------------------------------------------------------
// Kernel 3 (main path): double-buffered 2-phase GEMM on pre-converted bf16.
// 128x128 tile, BK=32, 4 waves (2x2). Rolled loop, no setprio. XCD-chunked
// block remap (bijective, 1024%8==0).
// ---------------------------------------------------------------------------
__global__ __launch_bounds__(256)
void rbf_gemm_bf16(const short* __restrict__ Abf, const short* __restrict__ Bbf,
                   const float* __restrict__ x2, const float* __restrict__ c2,
                   const float* __restrict__ ls, const float* __restrict__ fcw,
                   float* __restrict__ part) {
    __shared__ short As[2][128 * 32];
    __shared__ short Bs[2][128 * 32];

    const int t    = threadIdx.x;
    const int lane = t & 63, wave = t >> 6;
    const int wr = wave >> 1, wc = wave & 1;
    const int lc = lane & 15, kg = lane >> 4;

    const int orig = blockIdx.x;
    const int wg   = (orig >> 3) + (orig & 7) * (1024 / 8);
    const int bm = wg >> 3, bn = wg & 7;

    const int srow = wave * 16 + (lane >> 2);
    const int scol = (lane & 3) * 8;
    const short* gA = Abf + (size_t)(bm * 128 + srow) * NK + scol;
    const short* gB = Bbf + (size_t)(bn * 128 + srow) * NK + scol;

#define STAGE(buf, kt)                                                          \
    _Pragma("unroll")                                                           \
    for (int j = 0; j < 2; ++j) {                                               \
        __builtin_amdgcn_global_load_lds(                                       \
            (const __attribute__((address_space(1))) unsigned int*)(gA + (size_t)j * 64 * NK + (kt) * 32), \
            (__attribute__((address_space(3))) unsigned int*)(&As[buf][wave * 512 + j * 2048]), \
            16, 0, 0);                                                          \
        __builtin_amdgcn_global_load_lds(                                       \
            (const __attribute__((address_space(1))) unsigned int*)(gB + (size_t)j * 64 * NK + (kt) * 32), \
            (__attribute__((address_space(3))) unsigned int*)(&Bs[buf][wave * 512 + j * 2048]), \
            16, 0, 0);                                                          \
    }

    f32x4 acc[4][4];
#pragma unroll
    for (int i = 0; i < 4; ++i)
#pragma unroll
        for (int j = 0; j < 4; ++j)
#pragma unroll
            for (int k = 0; k < 4; ++k) acc[i][j][k] = 0.f;

    const int aoff = (wr * 64 + lc) * 32 + kg * 8;
    const int boff = (wc * 64 + lc) * 32 + kg * 8;

#define COMPUTE(buf)                                                            \
    {                                                                           \
        s16x8 af[4], bfv[4];                                                    \
        _Pragma("unroll")                                                       \
        for (int mi = 0; mi < 4; ++mi) af[mi]  = *(const s16x8*)(&As[buf][aoff + mi * 512]); \
        _Pragma("unroll")                                                       \
        for (int ni = 0; ni < 4; ++ni) bfv[ni] = *(const s16x8*)(&Bs[buf][boff + ni * 512]); \
        _Pragma("unroll")                                                       \
        for (int mi = 0; mi < 4; ++mi)                                          \
            _Pragma("unroll")                                                   \
            for (int ni = 0; ni < 4; ++ni)                                      \
                acc[mi][ni] = __builtin_amdgcn_mfma_f32_16x16x32_bf16(          \
                    af[mi], bfv[ni], acc[mi][ni], 0, 0, 0);                     \
    }

    STAGE(0, 0);
    __syncthreads();
    for (int kt = 0; kt < NK / 32; kt += 2) {
        STAGE(1, kt + 1);
        COMPUTE(0);
        __syncthreads();
        if (kt + 2 < NK / 32) STAGE(0, kt + 2);
        COMPUTE(1);
        __syncthreads();
    }
#undef STAGE
#undef COMPUTE

    rbf_epilogue_part(acc, x2, c2, ls, fcw, part, bm, bn, wr, wc, lc, kg);
}

// ---------------------------------------------------------------------------
// Fallback (ws too small): f32 reg-staged, atomic epilogue.
// ---------------------------------------------------------------------------
__global__ __launch_bounds__(256)
void rbf_gemm_f32(const float* __restrict__ X, const float* __restrict__ Cn,
                  const float* __restrict__ x2, const float* __restrict__ c2,
                  const float* __restrict__ ls, const float* __restrict__ fcw,
                  float* __restrict__ out) {
    __shared__ short As[128 * 40];
    __shared__ short Bs[128 * 40];

    const int t    = threadIdx.x;
    const int lane = t & 63, wave = t >> 6;
    const int wr = wave >> 1, wc = wave & 1;
    const int lc = lane & 15, kg = lane >> 4;
    const int bn = blockIdx.x & 7, bm = blockIdx.x >> 3;

    const int srow = t >> 1, shalf = t & 1;
    const float* pA = X  + (size_t)(bm * 128 + srow) * NK + shalf * 16;
    const float* pB = Cn + (size_t)(bn * 128 + srow) * NK + shalf * 16;
    const int sbase = srow * 40 + shalf * 16;

    f32x4 ra[4], rb[4];
#pragma unroll
    for (int i = 0; i < 4; ++i) {
        ra[i] = *(const f32x4*)(pA + i * 4);
        rb[i] = *(const f32x4*)(pB + i * 4);
    }

    f32x4 acc[4][4];
#pragma unroll
    for (int i = 0; i < 4; ++i)
#pragma unroll
        for (int j = 0; j < 4; ++j)
#pragma unroll
            for (int k = 0; k < 4; ++k) acc[i][j][k] = 0.f;

    const short* Ab = As + (wr * 64 + lc) * 40 + kg * 8;
    const short* Bb = Bs + (wc * 64 + lc) * 40 + kg * 8;

    for (int kt = 0; kt < NK / 32; ++kt) {
        __syncthreads();
        s16x8 va0, va1, vb0, vb1;
#pragma unroll
        for (int i = 0; i < 8; ++i) {
            va0[i] = f2bf(ra[i >> 2][i & 3]);
            va1[i] = f2bf(ra[2 + (i >> 2)][i & 3]);
            vb0[i] = f2bf(rb[i >> 2][i & 3]);
            vb1[i] = f2bf(rb[2 + (i >> 2)][i & 3]);
        }
        *(s16x8*)&As[sbase]     = va0;
        *(s16x8*)&As[sbase + 8] = va1;
        *(s16x8*)&Bs[sbase]     = vb0;
        *(s16x8*)&Bs[sbase + 8] = vb1;
        __syncthreads();

        if (kt + 1 < NK / 32) {
            const float* qA = pA + (kt + 1) * 32;
            const float* qB = pB + (kt + 1) * 32;
#pragma unroll
            for (int i = 0; i < 4; ++i) {
                ra[i] = *(const f32x4*)(qA + i * 4);
                rb[i] = *(const f32x4*)(qB + i * 4);
            }
        }

        s16x8 af[4], bfv[4];
#pragma unroll
        for (int mi = 0; mi < 4; ++mi) af[mi]  = *(const s16x8*)(Ab + mi * 16 * 40);
#pragma unroll
        for (int ni = 0; ni < 4; ++ni) bfv[ni] = *(const s16x8*)(Bb + ni * 16 * 40);
#pragma unroll
        for (int mi = 0; mi < 4; ++mi)
#pragma unroll
            for (int ni = 0; ni < 4; ++ni)
                acc[mi][ni] = __builtin_amdgcn_mfma_f32_16x16x32_bf16(
                    af[mi], bfv[ni], acc[mi][ni], 0, 0, 0);
    }

    rbf_epilogue_atomic(acc, x2, c2, ls, fcw, out, bm, bn, wr, wc, lc, kg);
}

// ---------------------------------------------------------------------------
extern "C" void kernel_launch(void* const* d_in, const int* in_sizes, int n_in,
                              void* d_out, int out_size, void* d_ws, size_t ws_size,
                              hipStream_t stream) {
    const float* X   = (const float*)d_in[0];   // [16384, 512]
    const float* Cn  = (const float*)d_in[1];   // [1024, 512]
    const float* ls  = (const float*)d_in[2];   // [1024]
    const float* fcw = (const float*)d_in[3];   // [5, 1024]
    const float* fcb = (const float*)d_in[4];   // [5]
    float* out = (float*)d_out;                 // [16384, 5]

    const size_t xbf_e  = (size_t)NB * NK;          // shorts
    const size_t cbf_e  = (size_t)NO * NK;          // shorts
    const size_t part_e = (size_t)NSL * NB * NC;    // f32
    const size_t need   = (xbf_e + cbf_e) * 2 + (NB + NO) * 4 + part_e * 4;

    if (ws_size >= need) {
        short* xbf  = (short*)d_ws;
        short* cbf  = xbf + xbf_e;
        float* x2   = (float*)(cbf + cbf_e);
        float* c2   = x2 + NB;
        float* part = c2 + NO;
        prep_bf16<<<(NB + NO + 3) / 4, 256, 0, stream>>>(X, Cn, xbf, cbf, x2, c2);
        rbf_gemm_bf16<<<(NO / 128) * (NB / 128), 256, 0, stream>>>(xbf, cbf, x2, c2, ls, fcw, part);
        reduce_out<<<(NB * NC / 4 + 255) / 256, 256, 0, stream>>>(part, fcb, out);
    } else {
        float* x2 = (float*)d_ws;
        float* c2 = x2 + NB;
        init_out<<<(NB * NC + 255) / 256, 256, 0, stream>>>(out, fcb);
        prep_f32<<<(NB + NO + 3) / 4, 256, 0, stream>>>(X, Cn, x2, c2);
        rbf_gemm_f32<<<(NO / 128) * (NB / 128), 256, 0, stream>>>(X, Cn, x2, c2, ls, fcw, out);
    }
}

// Round 5
// 122.556 us; speedup vs baseline: 1.9955x; 1.0606x over previous
//
#include <hip/hip_runtime.h>
#include <hip/hip_bf16.h>
#include <cmath>

#define NB 16384   // batch rows
#define NK 512     // in features
#define NO 1024    // out features (centres)
#define NC 5       // classes
#define NSL 16     // partial slices = 4 bn-blocks x 4 wave-cols
#define NT 16      // K-tiles (NK/32)

typedef float f32x4 __attribute__((ext_vector_type(4)));
typedef short s16x8 __attribute__((ext_vector_type(8)));

__device__ inline short f2bf(float f) {
    union { __hip_bfloat16 h; short s; } u;
    u.h = __float2bfloat16(f);
    return u.s;
}

// ---------------------------------------------------------------------------
// Kernel 1: fused row sum-of-squares (f32) + bf16 conversion of X and C.
// ---------------------------------------------------------------------------
__global__ void prep_bf16(const float* __restrict__ x, const float* __restrict__ c,
                          short* __restrict__ xbf, short* __restrict__ cbf,
                          float* __restrict__ x2, float* __restrict__ c2) {
    int gw   = (blockIdx.x * blockDim.x + threadIdx.x) >> 6;
    int lane = threadIdx.x & 63;
    if (gw >= NB + NO) return;
    bool isX = gw < NB;
    const float* src = isX ? (x + (size_t)gw * NK) : (c + (size_t)(gw - NB) * NK);
    short*       dst = isX ? (xbf + (size_t)gw * NK) : (cbf + (size_t)(gw - NB) * NK);
    f32x4 v0 = *(const f32x4*)(src + lane * 8);
    f32x4 v1 = *(const f32x4*)(src + lane * 8 + 4);
    s16x8 o;
    float s = 0.f;
#pragma unroll
    for (int j = 0; j < 4; ++j) {
        s += v0[j] * v0[j] + v1[j] * v1[j];
        o[j]     = f2bf(v0[j]);
        o[4 + j] = f2bf(v1[j]);
    }
    *(s16x8*)(dst + lane * 8) = o;
#pragma unroll
    for (int off = 1; off < 64; off <<= 1) s += __shfl_xor(s, off);
    if (lane == 0) {
        if (isX) x2[gw] = s;
        else     c2[gw - NB] = s;
    }
}

// Standalone prep for the fallback path.
__global__ void prep_f32(const float* __restrict__ x, const float* __restrict__ c,
                         float* __restrict__ x2, float* __restrict__ c2) {
    int gw   = (blockIdx.x * blockDim.x + threadIdx.x) >> 6;
    int lane = threadIdx.x & 63;
    if (gw >= NB + NO) return;
    const float* src = (gw < NB) ? (x + (size_t)gw * NK)
                                 : (c + (size_t)(gw - NB) * NK);
    f32x4 v0 = *(const f32x4*)(src + lane * 8);
    f32x4 v1 = *(const f32x4*)(src + lane * 8 + 4);
    float s = 0.f;
#pragma unroll
    for (int j = 0; j < 4; ++j) s += v0[j] * v0[j] + v1[j] * v1[j];
#pragma unroll
    for (int off = 1; off < 64; off <<= 1) s += __shfl_xor(s, off);
    if (lane == 0) {
        if (gw < NB) x2[gw] = s;
        else         c2[gw - NB] = s;
    }
}

// ---------------------------------------------------------------------------
// Kernel 2 (fallback only): out[b][n] = fc_b[n].
// ---------------------------------------------------------------------------
__global__ void init_out(float* __restrict__ out, const float* __restrict__ fcb) {
    int i = blockIdx.x * blockDim.x + threadIdx.x;
    if (i < NB * NC) out[i] = fcb[i % NC];
}

// ---------------------------------------------------------------------------
// Kernel 4: sum 16 partial slices + bias -> out.  part[NSL][NB*NC].
// ---------------------------------------------------------------------------
__global__ void reduce_out(const float* __restrict__ part,
                           const float* __restrict__ fcb,
                           float* __restrict__ out) {
    int i = blockIdx.x * blockDim.x + threadIdx.x;   // group of 4 f32
    if (i >= NB * NC / 4) return;
    f32x4 s = {0.f, 0.f, 0.f, 0.f};
#pragma unroll
    for (int sl = 0; sl < NSL; ++sl)
        s += *(const f32x4*)(part + (size_t)sl * NB * NC + i * 4);
    f32x4 o;
#pragma unroll
    for (int j = 0; j < 4; ++j) o[j] = s[j] + fcb[(i * 4 + j) % NC];
    *(f32x4*)(out + i * 4) = o;
}

// ---------------------------------------------------------------------------
// Kernel 3 (main): 256x256 tile, 8 waves (2M x 4N), BK=32, 4 LDS K-tile
// buffers, counted-vmcnt pipeline (prefetch distance 2, never vmcnt(0) in
// steady state). XOR-swizzled LDS (chunk-bit0 ^= chunk-bit3) applied on the
// pre-swizzled GLOBAL source + the swizzled ds_read address; gload_lds dest
// stays linear (rule #21). Grid = 256 = 1 block/CU; XCD-chunked remap.
// ---------------------------------------------------------------------------
__global__ __launch_bounds__(512, 2)
void rbf_gemm_256(const short* __restrict__ Abf, const short* __restrict__ Bbf,
                  const float* __restrict__ x2, const float* __restrict__ c2,
                  const float* __restrict__ ls, const float* __restrict__ fcw,
                  float* __restrict__ part) {
    __shared__ short As[4][256 * 32];   // 4 x 16KB
    __shared__ short Bs[4][256 * 32];   // 4 x 16KB

    const int t    = threadIdx.x;
    const int lane = t & 63, wave = t >> 6;
    const int wr  = wave >> 2, wcn = wave & 3;   // 2 x 4 wave grid
    const int lr  = lane & 15, kg  = lane >> 4;

    // XCD-chunked remap: 256 blocks, 32 consecutive wg per XCD.
    const int orig = blockIdx.x;
    const int wg   = (orig & 7) * 32 + (orig >> 3);
    const int bm = wg >> 2, bn = wg & 3;

    // ---- staging (pre-swizzled global source, linear LDS dest) ----
    // chunk c = j*512 + t holds logical chunk c ^ ((c>>3)&1); bit3(c)=bit3(t).
    const int tc   = t ^ ((t >> 3) & 1);
    const int srow = tc >> 2;            // 0..127  (j adds 128)
    const int scol = (tc & 3) * 8;       // shorts
    const short* gA = Abf + (size_t)(bm * 256 + srow) * NK + scol;
    const short* gB = Bbf + (size_t)(bn * 256 + srow) * NK + scol;

    // ---- fragment-read offsets (swizzled): kg*8 ^ (row-bit1 << 3) ----
    const int akoff = (kg * 8) ^ ((lane & 2) << 2);
    const int arow0 = wr * 128 + lr;     // + mi*16
    const int brow0 = wcn * 64 + lr;     // + ni*16

    f32x4 acc[8][4];
#pragma unroll
    for (int i = 0; i < 8; ++i)
#pragma unroll
        for (int j = 0; j < 4; ++j)
#pragma unroll
            for (int k = 0; k < 4; ++k) acc[i][j][k] = 0.f;

#define STAGE_A(kt)                                                             \
    _Pragma("unroll")                                                           \
    for (int j = 0; j < 2; ++j)                                                 \
        __builtin_amdgcn_global_load_lds(                                       \
            (const __attribute__((address_space(1))) unsigned int*)(gA + (size_t)j * 128 * NK + (kt) * 32), \
            (__attribute__((address_space(3))) unsigned int*)(&As[(kt) & 3][j * 4096 + wave * 512]), \
            16, 0, 0);

#define STAGE_B(kt)                                                             \
    _Pragma("unroll")                                                           \
    for (int j = 0; j < 2; ++j)                                                 \
        __builtin_amdgcn_global_load_lds(                                       \
            (const __attribute__((address_space(1))) unsigned int*)(gB + (size_t)j * 128 * NK + (kt) * 32), \
            (__attribute__((address_space(3))) unsigned int*)(&Bs[(kt) & 3][j * 4096 + wave * 512]), \
            16, 0, 0);

// Tile body: phase A = ds_read B(4)+A(0..3), stage A(t+2), 16 MFMA;
//            phase B = ds_read A(4..7),      stage B(t+2), 16 MFMA.
#define TILE_BODY(b, kt2, DOSTAGE)                                              \
    {                                                                           \
        const short* Ab = &As[b][0];                                            \
        const short* Bb = &Bs[b][0];                                            \
        s16x8 bfr[4], afr[4];                                                   \
        _Pragma("unroll")                                                       \
        for (int ni = 0; ni < 4; ++ni)                                          \
            bfr[ni] = *(const s16x8*)(Bb + (brow0 + ni * 16) * 32 + akoff);     \
        _Pragma("unroll")                                                       \
        for (int mi = 0; mi < 4; ++mi)                                          \
            afr[mi] = *(const s16x8*)(Ab + (arow0 + mi * 16) * 32 + akoff);     \
        if (DOSTAGE) { STAGE_A(kt2); }                                          \
        __builtin_amdgcn_s_setprio(1);                                          \
        _Pragma("unroll")                                                       \
        for (int mi = 0; mi < 4; ++mi)                                          \
            _Pragma("unroll")                                                   \
            for (int ni = 0; ni < 4; ++ni)                                      \
                acc[mi][ni] = __builtin_amdgcn_mfma_f32_16x16x32_bf16(          \
                    afr[mi], bfr[ni], acc[mi][ni], 0, 0, 0);                    \
        __builtin_amdgcn_s_setprio(0);                                          \
        _Pragma("unroll")                                                       \
        for (int mi = 0; mi < 4; ++mi)                                          \
            afr[mi] = *(const s16x8*)(Ab + (arow0 + (mi + 4) * 16) * 32 + akoff); \
        if (DOSTAGE) { STAGE_B(kt2); }                                          \
        __builtin_amdgcn_s_setprio(1);                                          \
        _Pragma("unroll")                                                       \
        for (int mi = 0; mi < 4; ++mi)                                          \
            _Pragma("unroll")                                                   \
            for (int ni = 0; ni < 4; ++ni)                                      \
                acc[mi + 4][ni] = __builtin_amdgcn_mfma_f32_16x16x32_bf16(      \
                    afr[mi], bfr[ni], acc[mi + 4][ni], 0, 0, 0);                \
        __builtin_amdgcn_s_setprio(0);                                          \
    }

    // prologue: tiles 0,1 in flight (8 loads); tile 0 resident after vmcnt(4)
    STAGE_A(0); STAGE_B(0);
    STAGE_A(1); STAGE_B(1);
    asm volatile("s_waitcnt vmcnt(4)" ::: "memory");
    __builtin_amdgcn_s_barrier();
    __builtin_amdgcn_sched_barrier(0);

    for (int kt = 0; kt < NT - 2; ++kt) {
        TILE_BODY(kt & 3, kt + 2, true);
        // outstanding: tile kt+1 (4) + tile kt+2 (4) -> drain kt+1's only
        asm volatile("s_waitcnt vmcnt(4)" ::: "memory");
        __builtin_amdgcn_s_barrier();
        __builtin_amdgcn_sched_barrier(0);
    }
    TILE_BODY((NT - 2) & 3, 0, false);
    asm volatile("s_waitcnt vmcnt(0)" ::: "memory");
    __builtin_amdgcn_s_barrier();
    __builtin_amdgcn_sched_barrier(0);
    TILE_BODY((NT - 1) & 3, 0, false);

#undef TILE_BODY
#undef STAGE_A
#undef STAGE_B

    // ---- epilogue: sq -> basis -> per-wave 64-col partial -> slice store ----
    // C frag (16x16x32): col = lane&15, row = (lane>>4)*4 + reg
    const int growb0 = bm * 256 + wr * 128 + kg * 4;  // + mi*16 + r
    const int gcol0  = bn * 256 + wcn * 64 + lr;      // + ni*16
    float* slice = part + (size_t)(bn * 4 + wcn) * NB * NC;

    float c2v[4], invs2[4], w[4][5];
#pragma unroll
    for (int ni = 0; ni < 4; ++ni) {
        int gc = gcol0 + ni * 16;
        c2v[ni]   = c2[gc];
        invs2[ni] = expf(-2.f * ls[gc]);   // 1/sigma^2; basis = exp(-sq/sigma^2)
#pragma unroll
        for (int n = 0; n < 5; ++n) w[ni][n] = fcw[n * NO + gc];
    }

#pragma unroll
    for (int mi = 0; mi < 8; ++mi) {
        float rs[4][5];
#pragma unroll
        for (int r = 0; r < 4; ++r)
#pragma unroll
            for (int n = 0; n < 5; ++n) rs[r][n] = 0.f;

#pragma unroll
        for (int r = 0; r < 4; ++r) {
            float x2v = x2[growb0 + mi * 16 + r];
#pragma unroll
            for (int ni = 0; ni < 4; ++ni) {
                float sq    = fmaxf(x2v + c2v[ni] - 2.f * acc[mi][ni][r], 0.f);
                float basis = expf(-sq * invs2[ni]);
#pragma unroll
                for (int n = 0; n < 5; ++n) rs[r][n] += basis * w[ni][n];
            }
        }
#pragma unroll
        for (int off = 1; off < 16; off <<= 1)
#pragma unroll
            for (int r = 0; r < 4; ++r)
#pragma unroll
                for (int n = 0; n < 5; ++n) rs[r][n] += __shfl_xor(rs[r][n], off);

        if (lr == 0) {
            float* dst = slice + (size_t)(growb0 + mi * 16) * NC;
            f32x4 v0 = {rs[0][0], rs[0][1], rs[0][2], rs[0][3]};
            f32x4 v1 = {rs[0][4], rs[1][0], rs[1][1], rs[1][2]};
            f32x4 v2 = {rs[1][3], rs[1][4], rs[2][0], rs[2][1]};
            f32x4 v3 = {rs[2][2], rs[2][3], rs[2][4], rs[3][0]};
            f32x4 v4 = {rs[3][1], rs[3][2], rs[3][3], rs[3][4]};
            *(f32x4*)(dst)      = v0;
            *(f32x4*)(dst + 4)  = v1;
            *(f32x4*)(dst + 8)  = v2;
            *(f32x4*)(dst + 12) = v3;
            *(f32x4*)(dst + 16) = v4;
        }
    }
}

// ---------------------------------------------------------------------------
// Fallback (ws too small): f32 reg-staged, atomic epilogue (round-1 proven).
// ---------------------------------------------------------------------------
__device__ inline void rbf_epilogue_atomic(f32x4 acc[4][4],
                                           const float* __restrict__ x2,
                                           const float* __restrict__ c2,
                                           const float* __restrict__ ls,
                                           const float* __restrict__ fcw,
                                           float* __restrict__ out,
                                           int bm, int bn, int wr, int wc,
                                           int lc, int kg) {
    const int growb0 = bm * 128 + wr * 64 + kg * 4;
    const int gcol0  = bn * 128 + wc * 64 + lc;
    float c2v[4], invs2[4], w[4][5];
#pragma unroll
    for (int ni = 0; ni < 4; ++ni) {
        int gc = gcol0 + ni * 16;
        c2v[ni]   = c2[gc];
        invs2[ni] = expf(-2.f * ls[gc]);
#pragma unroll
        for (int n = 0; n < 5; ++n) w[ni][n] = fcw[n * NO + gc];
    }
#pragma unroll
    for (int mi = 0; mi < 4; ++mi) {
        float rs[4][5];
#pragma unroll
        for (int r = 0; r < 4; ++r)
#pragma unroll
            for (int n = 0; n < 5; ++n) rs[r][n] = 0.f;
#pragma unroll
        for (int r = 0; r < 4; ++r) {
            float x2v = x2[growb0 + mi * 16 + r];
#pragma unroll
            for (int ni = 0; ni < 4; ++ni) {
                float sq    = fmaxf(x2v + c2v[ni] - 2.f * acc[mi][ni][r], 0.f);
                float basis = expf(-sq * invs2[ni]);
#pragma unroll
                for (int n = 0; n < 5; ++n) rs[r][n] += basis * w[ni][n];
            }
        }
#pragma unroll
        for (int off = 1; off < 16; off <<= 1)
#pragma unroll
            for (int r = 0; r < 4; ++r)
#pragma unroll
                for (int n = 0; n < 5; ++n) rs[r][n] += __shfl_xor(rs[r][n], off);
        if (lc == 0) {
#pragma unroll
            for (int r = 0; r < 4; ++r) {
                int grow = growb0 + mi * 16 + r;
#pragma unroll
                for (int n = 0; n < 5; ++n)
                    atomicAdd(&out[(size_t)grow * NC + n], rs[r][n]);
            }
        }
    }
}

__global__ __launch_bounds__(256)
void rbf_gemm_f32(const float* __restrict__ X, const float* __restrict__ Cn,
                  const float* __restrict__ x2, const float* __restrict__ c2,
                  const float* __restrict__ ls, const float* __restrict__ fcw,
                  float* __restrict__ out) {
    __shared__ short As[128 * 40];
    __shared__ short Bs[128 * 40];

    const int t    = threadIdx.x;
    const int lane = t & 63, wave = t >> 6;
    const int wr = wave >> 1, wc = wave & 1;
    const int lc = lane & 15, kg = lane >> 4;
    const int bn = blockIdx.x & 7, bm = blockIdx.x >> 3;

    const int srow = t >> 1, shalf = t & 1;
    const float* pA = X  + (size_t)(bm * 128 + srow) * NK + shalf * 16;
    const float* pB = Cn + (size_t)(bn * 128 + srow) * NK + shalf * 16;
    const int sbase = srow * 40 + shalf * 16;

    f32x4 ra[4], rb[4];
#pragma unroll
    for (int i = 0; i < 4; ++i) {
        ra[i] = *(const f32x4*)(pA + i * 4);
        rb[i] = *(const f32x4*)(pB + i * 4);
    }

    f32x4 acc[4][4];
#pragma unroll
    for (int i = 0; i < 4; ++i)
#pragma unroll
        for (int j = 0; j < 4; ++j)
#pragma unroll
            for (int k = 0; k < 4; ++k) acc[i][j][k] = 0.f;

    const short* Ab = As + (wr * 64 + lc) * 40 + kg * 8;
    const short* Bb = Bs + (wc * 64 + lc) * 40 + kg * 8;

    for (int kt = 0; kt < NK / 32; ++kt) {
        __syncthreads();
        s16x8 va0, va1, vb0, vb1;
#pragma unroll
        for (int i = 0; i < 8; ++i) {
            va0[i] = f2bf(ra[i >> 2][i & 3]);
            va1[i] = f2bf(ra[2 + (i >> 2)][i & 3]);
            vb0[i] = f2bf(rb[i >> 2][i & 3]);
            vb1[i] = f2bf(rb[2 + (i >> 2)][i & 3]);
        }
        *(s16x8*)&As[sbase]     = va0;
        *(s16x8*)&As[sbase + 8] = va1;
        *(s16x8*)&Bs[sbase]     = vb0;
        *(s16x8*)&Bs[sbase + 8] = vb1;
        __syncthreads();

        if (kt + 1 < NK / 32) {
            const float* qA = pA + (kt + 1) * 32;
            const float* qB = pB + (kt + 1) * 32;
#pragma unroll
            for (int i = 0; i < 4; ++i) {
                ra[i] = *(const f32x4*)(qA + i * 4);
                rb[i] = *(const f32x4*)(qB + i * 4);
            }
        }

        s16x8 af[4], bfv[4];
#pragma unroll
        for (int mi = 0; mi < 4; ++mi) af[mi]  = *(const s16x8*)(Ab + mi * 16 * 40);
#pragma unroll
        for (int ni = 0; ni < 4; ++ni) bfv[ni] = *(const s16x8*)(Bb + ni * 16 * 40);
#pragma unroll
        for (int mi = 0; mi < 4; ++mi)
#pragma unroll
            for (int ni = 0; ni < 4; ++ni)
                acc[mi][ni] = __builtin_amdgcn_mfma_f32_16x16x32_bf16(
                    af[mi], bfv[ni], acc[mi][ni], 0, 0, 0);
    }

    rbf_epilogue_atomic(acc, x2, c2, ls, fcw, out, bm, bn, wr, wc, lc, kg);
}

// ---------------------------------------------------------------------------
extern "C" void kernel_launch(void* const* d_in, const int* in_sizes, int n_in,
                              void* d_out, int out_size, void* d_ws, size_t ws_size,
                              hipStream_t stream) {
    const float* X   = (const float*)d_in[0];   // [16384, 512]
    const float* Cn  = (const float*)d_in[1];   // [1024, 512]
    const float* ls  = (const float*)d_in[2];   // [1024]
    const float* fcw = (const float*)d_in[3];   // [5, 1024]
    const float* fcb = (const float*)d_in[4];   // [5]
    float* out = (float*)d_out;                 // [16384, 5]

    const size_t xbf_e  = (size_t)NB * NK;          // shorts
    const size_t cbf_e  = (size_t)NO * NK;          // shorts
    const size_t part_e = (size_t)NSL * NB * NC;    // f32
    const size_t need   = (xbf_e + cbf_e) * 2 + (NB + NO) * 4 + part_e * 4;

    if (ws_size >= need) {
        short* xbf  = (short*)d_ws;
        short* cbf  = xbf + xbf_e;
        float* x2   = (float*)(cbf + cbf_e);
        float* c2   = x2 + NB;
        float* part = c2 + NO;
        prep_bf16<<<(NB + NO + 3) / 4, 256, 0, stream>>>(X, Cn, xbf, cbf, x2, c2);
        rbf_gemm_256<<<(NB / 256) * (NO / 256), 512, 0, stream>>>(xbf, cbf, x2, c2, ls, fcw, part);
        reduce_out<<<(NB * NC / 4 + 255) / 256, 256, 0, stream>>>(part, fcb, out);
    } else {
        float* x2 = (float*)d_ws;
        float* c2 = x2 + NB;
        init_out<<<(NB * NC + 255) / 256, 256, 0, stream>>>(out, fcb);
        prep_f32<<<(NB + NO + 3) / 4, 256, 0, stream>>>(X, Cn, x2, c2);
        rbf_gemm_f32<<<(NO / 128) * (NB / 128), 256, 0, stream>>>(X, Cn, x2, c2, ls, fcw, out);
    }
}